// Round 14
// baseline (324.024 us; speedup 1.0000x reference)
//
#include <hip/hip_runtime.h>

#define B    32
#define N1   1024
#define FIN  128
#define NH   256
#define KP1  512
#define KP2  256
#define NCLS 10
#define MAXD 64
#define E1   1.7182818284590452f   // e^LAMB - 1, LAMB = 1.0

typedef float4 F4;
typedef __attribute__((ext_vector_type(8))) short bf16x8;
typedef __attribute__((ext_vector_type(4))) float f32x4;

__device__ __forceinline__ void fma4(F4& a, float s, F4 v) {
    a.x += s * v.x; a.y += s * v.y; a.z += s * v.z; a.w += s * v.w;
}
__device__ __forceinline__ void add4(F4& a, F4 v) {
    a.x += v.x; a.y += v.y; a.z += v.z; a.w += v.w;
}
__device__ __forceinline__ void max4(F4& a, F4 v) {
    a.x = fmaxf(a.x, v.x); a.y = fmaxf(a.y, v.y); a.z = fmaxf(a.z, v.z); a.w = fmaxf(a.w, v.w);
}
__device__ __forceinline__ unsigned short f2bf(float f) {
    unsigned int u = __float_as_uint(f);
    u += 0x7fffu + ((u >> 16) & 1u);
    return (unsigned short)(u >> 16);
}
__device__ __forceinline__ float bf2f(unsigned short h) {
    return __uint_as_float(((unsigned int)h) << 16);
}
__device__ __forceinline__ float wave_sum(float v) {
    v += __shfl_xor(v, 32); v += __shfl_xor(v, 16);
    v += __shfl_xor(v, 8);  v += __shfl_xor(v, 4);
    v += __shfl_xor(v, 2);  v += __shfl_xor(v, 1);
    return v;
}
// physical XCD id (0..7); masked for safety
__device__ __forceinline__ int xcc_id() {
    int x;
    asm volatile("s_getreg_b32 %0, hwreg(HW_REG_XCC_ID)" : "=s"(x));
    return x & 7;
}
// claim a chunk of 4 items from own XCD queue, else steal. PER % 4 == 0.
// returns global item id (queue*PER + g) or -1 when all queues drained.
__device__ __forceinline__ int claim4(int* ctr, int PER) {
    int x = xcc_id();
    int g = atomicAdd(&ctr[x], 4);
    if (g < PER) return x * PER + g;
    #pragma unroll
    for (int d = 1; d < 8; ++d) {
        int y = (x + d) & 7;
        g = atomicAdd(&ctr[y], 4);
        if (g < PER) return y * PER + g;
    }
    return -1;
}

// ---------------- W split into MFMA-fragment-order bf16 hi/lo (+ queue reset) ----------------
__global__ __launch_bounds__(256)
void wsplit_kernel(const float* __restrict__ W1, const float* __restrict__ W2,
                   const float* __restrict__ W3,
                   unsigned short* __restrict__ whi1, unsigned short* __restrict__ wlo1,
                   unsigned short* __restrict__ whi2, unsigned short* __restrict__ wlo2,
                   unsigned short* __restrict__ whi3, unsigned short* __restrict__ wlo3,
                   int* __restrict__ qctr) {
    if (blockIdx.x == 0 && threadIdx.x < 32) qctr[threadIdx.x] = 0;
    int T = blockIdx.x * 256 + threadIdx.x;   // 640 blocks -> 163840 elems
    const float* W; unsigned short *hi, *lo; int idx, kd;
    if (T < 32768)      { W = W1; hi = whi1; lo = wlo1; idx = T;         kd = 128; }
    else if (T < 98304) { W = W2; hi = whi2; lo = wlo2; idx = T - 32768; kd = 256; }
    else                { W = W3; hi = whi3; lo = wlo3; idx = T - 98304; kd = 256; }
    int e = idx & 7, lane = (idx >> 3) & 63;
    int nks = kd >> 5;
    int ks = (idx >> 9) & (nks - 1);
    int nt = idx >> ((nks == 4) ? 11 : 12);
    int k = ks * 32 + ((lane >> 4) << 3) + e;
    int j = nt * 16 + (lane & 15);
    float v = W[k * 256 + j];
    unsigned short h = f2bf(v);
    hi[idx] = h;
    lo[idx] = f2bf(v - bf2f(h));
}

// ---------------- MFMA GEMM body: out[32rows,256] = A @ W, bf16x3 split ----------------
template<int KD, int KLOG>
__device__ __forceinline__ void gemm_body(char* smem, const float* __restrict__ A,
                                          const int* __restrict__ gidx, int nsrc,
                                          const unsigned short* __restrict__ Whi,
                                          const unsigned short* __restrict__ Wlo,
                                          float* __restrict__ out, int blk) {
    constexpr int NKS = KD / 32;
    typedef unsigned short u16;
    auto ahi = (u16(*)[KD + 8])smem;
    auto alo = (u16(*)[KD + 8])(smem + sizeof(u16) * 32 * (KD + 8));
    int tid = threadIdx.x;
    int m0 = blk * 32;
    for (int i = tid; i < 32 * (KD / 4); i += 256) {
        int r = i / (KD / 4), c = i % (KD / 4);
        const float4* Arow;
        if (KLOG < 0) {
            Arow = (const float4*)(A + (size_t)(m0 + r) * KD);
        } else {
            int gr = m0 + r;
            int bb = gr >> (KLOG < 0 ? 0 : KLOG);
            Arow = (const float4*)(A + ((size_t)bb * nsrc + gidx[gr]) * KD);
        }
        float4 v = Arow[c];
        int k = c * 4;
        unsigned short h0 = f2bf(v.x), h1 = f2bf(v.y), h2 = f2bf(v.z), h3 = f2bf(v.w);
        *(uint2*)&ahi[r][k] = make_uint2((unsigned)h0 | ((unsigned)h1 << 16),
                                         (unsigned)h2 | ((unsigned)h3 << 16));
        unsigned short l0 = f2bf(v.x - bf2f(h0)), l1 = f2bf(v.y - bf2f(h1));
        unsigned short l2 = f2bf(v.z - bf2f(h2)), l3 = f2bf(v.w - bf2f(h3));
        *(uint2*)&alo[r][k] = make_uint2((unsigned)l0 | ((unsigned)l1 << 16),
                                         (unsigned)l2 | ((unsigned)l3 << 16));
    }
    __syncthreads();
    int lane = tid & 63, wv = tid >> 6;
    int ln15 = lane & 15, q = lane >> 4;
    f32x4 acc[2][4] = {};
    const bf16x8* WH = (const bf16x8*)Whi;
    const bf16x8* WL = (const bf16x8*)Wlo;
    for (int ks = 0; ks < NKS; ++ks) {
        int kb = ks * 32 + q * 8;
        bf16x8 a0h = *(const bf16x8*)&ahi[ln15][kb];
        bf16x8 a0l = *(const bf16x8*)&alo[ln15][kb];
        bf16x8 a1h = *(const bf16x8*)&ahi[ln15 + 16][kb];
        bf16x8 a1l = *(const bf16x8*)&alo[ln15 + 16][kb];
        #pragma unroll
        for (int t = 0; t < 4; ++t) {
            int nt = wv * 4 + t;
            size_t off = (size_t)(nt * NKS + ks) * 64 + lane;
            bf16x8 bh = WH[off];
            bf16x8 bl = WL[off];
            acc[0][t] = __builtin_amdgcn_mfma_f32_16x16x32_bf16(a0h, bh, acc[0][t], 0, 0, 0);
            acc[1][t] = __builtin_amdgcn_mfma_f32_16x16x32_bf16(a1h, bh, acc[1][t], 0, 0, 0);
            acc[0][t] = __builtin_amdgcn_mfma_f32_16x16x32_bf16(a0l, bh, acc[0][t], 0, 0, 0);
            acc[1][t] = __builtin_amdgcn_mfma_f32_16x16x32_bf16(a1l, bh, acc[1][t], 0, 0, 0);
            acc[0][t] = __builtin_amdgcn_mfma_f32_16x16x32_bf16(a0h, bl, acc[0][t], 0, 0, 0);
            acc[1][t] = __builtin_amdgcn_mfma_f32_16x16x32_bf16(a1h, bl, acc[1][t], 0, 0, 0);
        }
    }
    #pragma unroll
    for (int mi = 0; mi < 2; ++mi)
        #pragma unroll
        for (int t = 0; t < 4; ++t) {
            int col = wv * 64 + t * 16 + ln15;
            #pragma unroll
            for (int r = 0; r < 4; ++r)
                out[(size_t)(m0 + mi * 16 + q * 4 + r) * 256 + col] = acc[mi][t][r];
        }
}

// ---------------- CSR build body: wave-scan prefix, deterministic ----------------
__device__ __forceinline__ void csr_body(char* smem, const float* __restrict__ adj,
                                         int* __restrict__ cnt, int* __restrict__ nbr,
                                         float* __restrict__ dgi, float* __restrict__ dia,
                                         int row) {
    int* wtot = (int*)smem;
    const float* arow = adj + (size_t)row * N1;
    int t = threadIdx.x, lane = t & 63, wave = t >> 6;
    float4 v4 = ((const float4*)arow)[t];
    int loc[4];
    int c = 0;
    if (v4.x > 0.5f) loc[c++] = t * 4 + 0;
    if (v4.y > 0.5f) loc[c++] = t * 4 + 1;
    if (v4.z > 0.5f) loc[c++] = t * 4 + 2;
    if (v4.w > 0.5f) loc[c++] = t * 4 + 3;
    int x = c;
    #pragma unroll
    for (int s = 1; s < 64; s <<= 1) {
        int y = __shfl_up(x, s);
        if (lane >= s) x += y;
    }
    if (lane == 63) wtot[wave] = x;
    __syncthreads();
    int base = 0;
    #pragma unroll
    for (int w = 0; w < 4; ++w) base += (w < wave) ? wtot[w] : 0;
    int total = wtot[0] + wtot[1] + wtot[2] + wtot[3];
    int off = base + x - c;
    for (int u = 0; u < c; ++u) {
        int p = off + u;
        if (p < MAXD) nbr[(size_t)row * MAXD + p] = loc[u];
    }
    if (t == 0) {
        cnt[row] = min(total, MAXD);
        dgi[row] = rsqrtf((float)total + 1.0f);
        dia[row] = total > 0 ? 1.0f / (float)total : 0.0f;
    }
}

// ---------------- merged: gemm1 [0,1024) | csr [1024,1024+B*N1) ----------------
__global__ __launch_bounds__(256, 4)
void k_gemm1_csr(const float* __restrict__ x, const unsigned short* __restrict__ whi1,
                 const unsigned short* __restrict__ wlo1, float* __restrict__ t1,
                 const float* __restrict__ adj, int* __restrict__ cnt,
                 int* __restrict__ nbr, float* __restrict__ dgi, float* __restrict__ dia) {
    __shared__ __align__(16) char smem[17408];
    if (blockIdx.x < 1024) gemm_body<FIN, -1>(smem, x, nullptr, 0, whi1, wlo1, t1, blockIdx.x);
    else                   csr_body(smem, adj, cnt, nbr, dgi, dia, blockIdx.x - 1024);
}

// ---------------- stage-1 GCN aggregate: XCD work-steal, 4 groups/block ----------------
__global__ __launch_bounds__(256)
void gcn1_kernel(const float* __restrict__ t1, const int* __restrict__ cnt,
                 const int* __restrict__ nbr, const float* __restrict__ dgi,
                 const float* __restrict__ b1, float* __restrict__ h1,
                 int* __restrict__ qctr) {
    __shared__ int sclaim;
    if (threadIdx.x == 0) sclaim = claim4(qctr, 1024);
    __syncthreads();
    int base = sclaim;
    if (base < 0) return;
    int lane = threadIdx.x & 63, wave = threadIdx.x >> 6;
    int xq = base >> 10, g0 = base & 1023;
    for (int it = 0; it < 4; ++it) {
        int local = g0 + it;
        int b = xq * 4 + (local >> 8);
        int g = local & 255;
        int i = g * 4 + wave;
        int row = (b << 10) + i;
        const F4* tb = (const F4*)(t1 + (((size_t)b << 10)) * NH);
        int n = cnt[row];
        int jv = 0; float dv = 0.f;
        if (lane < n) {
            jv = nbr[(size_t)row * MAXD + lane];
            dv = dgi[(b << 10) + jv];
        }
        F4 a[8];
        #pragma unroll
        for (int k = 0; k < 8; ++k) a[k] = make_float4(0, 0, 0, 0);
        int e = 0;
        for (; e + 8 <= n; e += 8) {
            int jj[8]; float dd[8];
            #pragma unroll
            for (int k = 0; k < 8; ++k) { jj[k] = __shfl(jv, e + k); dd[k] = __shfl(dv, e + k); }
            F4 v[8];
            #pragma unroll
            for (int k = 0; k < 8; ++k) v[k] = tb[(size_t)jj[k] * 64 + lane];
            #pragma unroll
            for (int k = 0; k < 8; ++k) fma4(a[k], dd[k], v[k]);
        }
        for (; e + 4 <= n; e += 4) {
            int jj[4]; float dd[4];
            #pragma unroll
            for (int k = 0; k < 4; ++k) { jj[k] = __shfl(jv, e + k); dd[k] = __shfl(dv, e + k); }
            #pragma unroll
            for (int k = 0; k < 4; ++k) fma4(a[k], dd[k], tb[(size_t)jj[k] * 64 + lane]);
        }
        for (; e < n; ++e) {
            int j = __shfl(jv, e); float d = __shfl(dv, e);
            fma4(a[0], d, tb[(size_t)j * 64 + lane]);
        }
        add4(a[0], a[1]); add4(a[2], a[3]); add4(a[4], a[5]); add4(a[6], a[7]);
        add4(a[0], a[2]); add4(a[4], a[6]); add4(a[0], a[4]);
        float di = dgi[row];
        F4 self = tb[(size_t)i * 64 + lane];
        F4 bb = ((const F4*)b1)[lane];
        F4 r;
        r.x = fmaxf(di * (a[0].x + di * self.x) + bb.x, 0.f);
        r.y = fmaxf(di * (a[0].y + di * self.y) + bb.y, 0.f);
        r.z = fmaxf(di * (a[0].z + di * self.z) + bb.z, 0.f);
        r.w = fmaxf(di * (a[0].w + di * self.w) + bb.w, 0.f);
        ((F4*)(h1 + (size_t)row * NH))[lane] = r;
    }
}

// ---------------- stage-1 info score: XCD work-steal, 4 groups/block ----------------
__global__ __launch_bounds__(256)
void info1_kernel(const float* __restrict__ h1, const int* __restrict__ cnt,
                  const int* __restrict__ nbr, const float* __restrict__ dia,
                  float* __restrict__ sc, int* __restrict__ qctr) {
    __shared__ int sclaim;
    if (threadIdx.x == 0) sclaim = claim4(qctr, 1024);
    __syncthreads();
    int base = sclaim;
    if (base < 0) return;
    int lane = threadIdx.x & 63, wave = threadIdx.x >> 6;
    int xq = base >> 10, g0 = base & 1023;
    for (int it = 0; it < 4; ++it) {
        int local = g0 + it;
        int b = xq * 4 + (local >> 8);
        int g = local & 255;
        int i = g * 4 + wave;
        int row = (b << 10) + i;
        const F4* hb = (const F4*)(h1 + (((size_t)b << 10)) * NH);
        int n = cnt[row];
        int jv = 0;
        if (lane < n) jv = nbr[(size_t)row * MAXD + lane];
        F4 a[8];
        #pragma unroll
        for (int k = 0; k < 8; ++k) a[k] = make_float4(0, 0, 0, 0);
        int e = 0;
        for (; e + 8 <= n; e += 8) {
            int jj[8];
            #pragma unroll
            for (int k = 0; k < 8; ++k) jj[k] = __shfl(jv, e + k);
            F4 v[8];
            #pragma unroll
            for (int k = 0; k < 8; ++k) v[k] = hb[(size_t)jj[k] * 64 + lane];
            #pragma unroll
            for (int k = 0; k < 8; ++k) add4(a[k], v[k]);
        }
        for (; e + 4 <= n; e += 4) {
            int jj[4];
            #pragma unroll
            for (int k = 0; k < 4; ++k) jj[k] = __shfl(jv, e + k);
            #pragma unroll
            for (int k = 0; k < 4; ++k) add4(a[k], hb[(size_t)jj[k] * 64 + lane]);
        }
        for (; e < n; ++e) {
            int j = __shfl(jv, e);
            add4(a[0], hb[(size_t)j * 64 + lane]);
        }
        add4(a[0], a[1]); add4(a[2], a[3]); add4(a[4], a[5]); add4(a[6], a[7]);
        add4(a[0], a[2]); add4(a[4], a[6]); add4(a[0], a[4]);
        float dd = dia[row];
        F4 self = hb[(size_t)i * 64 + lane];
        float val = fabsf(self.x - dd * a[0].x) + fabsf(self.y - dd * a[0].y)
                  + fabsf(self.z - dd * a[0].z) + fabsf(self.w - dd * a[0].w);
        val = wave_sum(val);
        if (lane == 0) sc[row] = val;
    }
}

// ---------------- top-k: hybrid shfl/LDS bitonic, 1 elem/thread ----------------
template<int NS, int KS, bool POS>
__global__ __launch_bounds__(NS)
void topk_kernel(const float* __restrict__ sc, int* __restrict__ idxo,
                 int* __restrict__ pos) {
    int b = blockIdx.x, tid = threadIdx.x;
    __shared__ float ss[NS];
    __shared__ int si[NS];
    float s = sc[b * NS + tid];
    int id = tid;
    for (int ksz = 2; ksz <= NS; ksz <<= 1) {
        for (int j = ksz >> 1; j > 0; j >>= 1) {
            float so; int io;
            if (j >= 64) {
                ss[tid] = s; si[tid] = id;
                __syncthreads();
                so = ss[tid ^ j]; io = si[tid ^ j];
                __syncthreads();
            } else {
                so = __shfl_xor(s, j); io = __shfl_xor(id, j);
            }
            bool mineFirst = (s > so) || (s == so && id < io);
            bool amLower = (tid & j) == 0;
            bool dirDesc = (tid & ksz) == 0;
            bool keep = dirDesc ? (amLower ? mineFirst : !mineFirst)
                                : (amLower ? !mineFirst : mineFirst);
            if (!keep) { s = so; id = io; }
        }
    }
    if (tid < KS) idxo[b * KS + tid] = id;
    if (POS) pos[b * NS + id] = (tid < KS) ? tid : -1;
}

// ---------------- attention r-dot over pooled rows (no copy) ----------------
__global__ __launch_bounds__(256)
void rv_kernel(const float* __restrict__ h, const int* __restrict__ idx,
               const float* __restrict__ att, float* __restrict__ rv, int K, int Nsrc) {
    int blk = blockIdx.x;
    int b = blk & 31, g = blk >> 5;
    int lane = threadIdx.x & 63, wave = threadIdx.x >> 6;
    int p = g * 4 + wave;
    int gg = b * K + p;
    int src = idx[gg];
    F4 v = ((const F4*)(h + ((size_t)b * Nsrc + src) * NH))[lane];
    F4 ar = ((const F4*)att)[64 + lane];
    float r2 = wave_sum(v.x * ar.x + v.y * ar.y + v.z * ar.z + v.w * ar.w);
    if (lane == 0) rv[gg] = r2;
}

// ---------------- readout body (gathers rows through idx): relu(max)/relu(mean) ----------------
template<int NROWS, bool INIT, int NSRC>
__device__ __forceinline__ void readout_body(char* smem, const float* __restrict__ h,
                                             const int* __restrict__ idx,
                                             float* __restrict__ rout, int blk) {
    auto rmx = (F4(*)[9])smem;
    auto rsm = (F4(*)[9])(smem + 32 * 9 * sizeof(F4));
    int b = blk & 31, ch = blk >> 5;
    int c = threadIdx.x & 7, rg = threadIdx.x >> 3;
    int f4 = ch * 8 + c;
    F4 mx = make_float4(-1e30f, -1e30f, -1e30f, -1e30f);
    F4 sm = make_float4(0, 0, 0, 0);
    for (int r = rg; r < NROWS; r += 32) {
        int src = idx[b * NROWS + r];
        F4 v = ((const F4*)(h + ((size_t)b * NSRC + src) * NH))[f4];
        max4(mx, v); add4(sm, v);
    }
    rmx[rg][c] = mx; rsm[rg][c] = sm;
    __syncthreads();
    for (int s = 16; s > 0; s >>= 1) {
        if (rg < s) {
            F4 m2 = rmx[rg + s][c], s2 = rsm[rg + s][c];
            max4(rmx[rg][c], m2); add4(rsm[rg][c], s2);
        }
        __syncthreads();
    }
    if (rg == 0) {
        F4 m = rmx[0][c], s4 = rsm[0][c];
        F4 rm, ra;
        rm.x = fmaxf(m.x, 0.f); rm.y = fmaxf(m.y, 0.f); rm.z = fmaxf(m.z, 0.f); rm.w = fmaxf(m.w, 0.f);
        const float inv = 1.0f / NROWS;
        ra.x = fmaxf(s4.x * inv, 0.f); ra.y = fmaxf(s4.y * inv, 0.f);
        ra.z = fmaxf(s4.z * inv, 0.f); ra.w = fmaxf(s4.w * inv, 0.f);
        F4* ro = (F4*)(rout + b * 512);
        if (INIT) {
            ro[f4] = rm; ro[64 + f4] = ra;
        } else {
            F4 o1 = ro[f4], o2 = ro[64 + f4];
            add4(o1, rm); add4(o2, ra);
            ro[f4] = o1; ro[64 + f4] = o2;
        }
    }
}

// ---------------- vexp body (256 threads, 2 elems each) ----------------
__device__ __forceinline__ void vexp_body(char* smem, const float* __restrict__ rv,
                                          float* __restrict__ v1, float* __restrict__ V1,
                                          int b) {
    float* red = (float*)smem;
    int t = threadIdx.x;
    float r0 = rv[b * KP1 + t], r1 = rv[b * KP1 + 256 + t];
    red[t] = fmaxf(r0, r1);
    __syncthreads();
    for (int s = 128; s > 0; s >>= 1) {
        if (t < s) red[t] = fmaxf(red[t], red[t + s]);
        __syncthreads();
    }
    float mx = red[0];
    __syncthreads();
    float e0 = expf(r0 - mx), e1 = expf(r1 - mx);
    v1[b * KP1 + t] = e0;
    v1[b * KP1 + 256 + t] = e1;
    red[t] = e0 + e1;
    __syncthreads();
    for (int s = 128; s > 0; s >>= 1) {
        if (t < s) red[t] += red[t + s];
        __syncthreads();
    }
    if (t == 0) V1[b] = red[0];
}

// ---------------- merged: readout1 [0,256) | vexp [256,288) ----------------
__global__ __launch_bounds__(256)
void k_readout1_vexp(const float* __restrict__ h1, const int* __restrict__ idx1,
                     float* __restrict__ rout, const float* __restrict__ rv,
                     float* __restrict__ v1, float* __restrict__ V1) {
    __shared__ __align__(16) char smem[9216];
    if (blockIdx.x < 256) readout_body<KP1, true, N1>(smem, h1, idx1, rout, blockIdx.x);
    else                  vexp_body(smem, rv, v1, V1, blockIdx.x - 256);
}

// ---------------- knbr body (4 waves/block) ----------------
__device__ __forceinline__ void knbr_body(const int* __restrict__ idx1, const int* __restrict__ cnt,
                                          const int* __restrict__ nbr, const int* __restrict__ pos1,
                                          const float* __restrict__ v1, const float* __restrict__ V1,
                                          int* __restrict__ knbr, int* __restrict__ kcnt,
                                          float* __restrict__ Z1, int j) {
    int b = j & 31, pg = j >> 5;
    int lane = threadIdx.x & 63, wave = threadIdx.x >> 6;
    int p = pg * 4 + wave;
    int g = b * KP1 + p;
    int ip = idx1[g];
    int n = cnt[b * N1 + ip];
    int q = -1;
    if (lane < n) {
        int jj = nbr[(size_t)(b * N1 + ip) * MAXD + lane];
        q = pos1[b * N1 + jj];
    }
    bool kept = q >= 0;
    unsigned long long mask = __ballot(kept);
    int off = __popcll(mask & ((1ull << lane) - 1ull));
    if (kept) knbr[(size_t)g * MAXD + off] = q;
    float s = kept ? v1[b * KP1 + q] : 0.f;
    s = wave_sum(s);
    if (lane == 0) { kcnt[g] = __popcll(mask); Z1[g] = V1[b] + E1 * s; }
}

// ---------------- merged: gemm2(gather h1) [0,512) | knbr [512,512+B*128) ----------------
__global__ __launch_bounds__(256, 4)
void k_gemm2_knbr(const float* __restrict__ h1, const unsigned short* __restrict__ whi2,
                  const unsigned short* __restrict__ wlo2, float* __restrict__ t2,
                  const int* __restrict__ idx1, const int* __restrict__ cnt,
                  const int* __restrict__ nbr, const int* __restrict__ pos1,
                  const float* __restrict__ v1, const float* __restrict__ V1,
                  int* __restrict__ knbr, int* __restrict__ kcnt, float* __restrict__ Z1) {
    __shared__ __align__(16) char smem[33792];
    if (blockIdx.x < 512)
        gemm_body<NH, 9>(smem, h1, idx1, N1, whi2, wlo2, t2, blockIdx.x);
    else knbr_body(idx1, cnt, nbr, pos1, v1, V1, knbr, kcnt, Z1, blockIdx.x - 512);
}

// ---------------- per-batch weighted column sum (partials over 8 chunks) ----------------
__global__ __launch_bounds__(256)
void wsum_kernel(const float* __restrict__ X, const float* __restrict__ v1,
                 float* __restrict__ wp) {
    int blk = blockIdx.x;
    int b = blk >> 3, c = blk & 7;
    int f = threadIdx.x;
    float a0 = 0.f, a1 = 0.f, a2 = 0.f, a3 = 0.f;
    for (int q = c * 64; q < c * 64 + 64; q += 4) {
        a0 += v1[b * KP1 + q + 0] * X[(size_t)(b * KP1 + q + 0) * NH + f];
        a1 += v1[b * KP1 + q + 1] * X[(size_t)(b * KP1 + q + 1) * NH + f];
        a2 += v1[b * KP1 + q + 2] * X[(size_t)(b * KP1 + q + 2) * NH + f];
        a3 += v1[b * KP1 + q + 3] * X[(size_t)(b * KP1 + q + 3) * NH + f];
    }
    wp[(size_t)blk * NH + f] = (a0 + a1) + (a2 + a3);
}

// ---------------- stage-2 GCN via factorized a1: XCD work-steal, 4 groups/block ----------------
__global__ __launch_bounds__(256)
void gcn2_kernel(const float* __restrict__ t2, const float* __restrict__ wp,
                 const float* __restrict__ v1, const float* __restrict__ Z1,
                 const int* __restrict__ knbr, const int* __restrict__ kcnt,
                 const float* __restrict__ b2, float* __restrict__ h2,
                 int* __restrict__ qctr) {
    __shared__ int sclaim;
    if (threadIdx.x == 0) sclaim = claim4(qctr, 512);
    __syncthreads();
    int base = sclaim;
    if (base < 0) return;
    int lane = threadIdx.x & 63, wave = threadIdx.x >> 6;
    int xq = base >> 9, g0 = base & 511;
    for (int it = 0; it < 4; ++it) {
        int local = g0 + it;
        int b = xq * 4 + (local >> 7);
        int g = local & 127;
        int p = g * 4 + wave;
        int gg = (b << 9) + p;
        const F4* tb = (const F4*)(t2 + (((size_t)b << 9)) * NH);
        int n = kcnt[gg];
        int jv = 0; float wv = 0.f;
        if (lane < n) {
            jv = knbr[(size_t)gg * MAXD + lane];
            wv = v1[(b << 9) + jv];
        }
        F4 a0 = make_float4(0,0,0,0), a1 = a0, a2 = a0, a3 = a0;
        int e = 0;
        for (; e + 4 <= n; e += 4) {
            int j0 = __shfl(jv, e), j1 = __shfl(jv, e+1), j2 = __shfl(jv, e+2), j3 = __shfl(jv, e+3);
            float d0 = __shfl(wv, e), d1 = __shfl(wv, e+1), d2 = __shfl(wv, e+2), d3 = __shfl(wv, e+3);
            fma4(a0, d0, tb[(size_t)j0 * 64 + lane]); fma4(a1, d1, tb[(size_t)j1 * 64 + lane]);
            fma4(a2, d2, tb[(size_t)j2 * 64 + lane]); fma4(a3, d3, tb[(size_t)j3 * 64 + lane]);
        }
        for (; e < n; ++e) {
            int j = __shfl(jv, e); float d = __shfl(wv, e);
            fma4(a0, d, tb[(size_t)j * 64 + lane]);
        }
        add4(a0, a1); add4(a2, a3); add4(a0, a2);
        F4 w = make_float4(0,0,0,0);
        #pragma unroll
        for (int c = 0; c < 8; ++c) add4(w, ((const F4*)wp)[(size_t)(b * 8 + c) * 64 + lane]);
        float zi = 1.0f / Z1[gg];
        F4 tv = tb[(size_t)p * 64 + lane];
        F4 bb = ((const F4*)b2)[lane];
        F4 r;
        r.x = fmaxf(0.5f * ((w.x + E1 * a0.x) * zi + tv.x) + bb.x, 0.f);
        r.y = fmaxf(0.5f * ((w.y + E1 * a0.y) * zi + tv.y) + bb.y, 0.f);
        r.z = fmaxf(0.5f * ((w.z + E1 * a0.z) * zi + tv.z) + bb.z, 0.f);
        r.w = fmaxf(0.5f * ((w.w + E1 * a0.w) * zi + tv.w) + bb.w, 0.f);
        ((F4*)(h2 + (size_t)gg * NH))[lane] = r;
    }
}

// ---------------- stage-2 info score via factorized a1: XCD work-steal ----------------
__global__ __launch_bounds__(256)
void info2_kernel(const float* __restrict__ h2, const float* __restrict__ wp,
                  const float* __restrict__ v1, const float* __restrict__ Z1,
                  const int* __restrict__ knbr, const int* __restrict__ kcnt,
                  float* __restrict__ sc, int* __restrict__ qctr) {
    __shared__ int sclaim;
    if (threadIdx.x == 0) sclaim = claim4(qctr, 512);
    __syncthreads();
    int base = sclaim;
    if (base < 0) return;
    int lane = threadIdx.x & 63, wave = threadIdx.x >> 6;
    int xq = base >> 9, g0 = base & 511;
    for (int it = 0; it < 4; ++it) {
        int local = g0 + it;
        int b = xq * 4 + (local >> 7);
        int g = local & 127;
        int p = g * 4 + wave;
        int gg = (b << 9) + p;
        const F4* hb = (const F4*)(h2 + (((size_t)b << 9)) * NH);
        int n = kcnt[gg];
        int jv = 0; float wv = 0.f;
        if (lane < n) {
            jv = knbr[(size_t)gg * MAXD + lane];
            wv = v1[(b << 9) + jv];
        }
        F4 a0 = make_float4(0,0,0,0), a1 = a0, a2 = a0, a3 = a0;
        int e = 0;
        for (; e + 4 <= n; e += 4) {
            int j0 = __shfl(jv, e), j1 = __shfl(jv, e+1), j2 = __shfl(jv, e+2), j3 = __shfl(jv, e+3);
            float d0 = __shfl(wv, e), d1 = __shfl(wv, e+1), d2 = __shfl(wv, e+2), d3 = __shfl(wv, e+3);
            fma4(a0, d0, hb[(size_t)j0 * 64 + lane]); fma4(a1, d1, hb[(size_t)j1 * 64 + lane]);
            fma4(a2, d2, hb[(size_t)j2 * 64 + lane]); fma4(a3, d3, hb[(size_t)j3 * 64 + lane]);
        }
        for (; e < n; ++e) {
            int j = __shfl(jv, e); float d = __shfl(wv, e);
            fma4(a0, d, hb[(size_t)j * 64 + lane]);
        }
        add4(a0, a1); add4(a2, a3); add4(a0, a2);
        F4 w = make_float4(0,0,0,0);
        #pragma unroll
        for (int c = 0; c < 8; ++c) add4(w, ((const F4*)wp)[(size_t)(b * 8 + c) * 64 + lane]);
        float zi = 1.0f / Z1[gg];
        F4 self = hb[(size_t)p * 64 + lane];
        float val = fabsf(self.x - (w.x + E1 * a0.x) * zi) + fabsf(self.y - (w.y + E1 * a0.y) * zi)
                  + fabsf(self.z - (w.z + E1 * a0.z) * zi) + fabsf(self.w - (w.w + E1 * a0.w) * zi);
        val = wave_sum(val);
        if (lane == 0) sc[gg] = val;
    }
}

// ---------------- a2 body: softmax(r2_q + a1k[p,q]) ----------------
__device__ __forceinline__ void a2_body(char* smem, const int* __restrict__ idx2,
                                        const float* __restrict__ rv, const float* __restrict__ v1,
                                        const float* __restrict__ Z1, const int* __restrict__ knbr,
                                        const int* __restrict__ kcnt, float* __restrict__ a2,
                                        int j) {
    unsigned char* flag = (unsigned char*)smem;
    float* red = (float*)(smem + 512);
    int b = j & 31, p = j >> 5;
    int g = b * KP2 + p;
    int q = threadIdx.x;
    int p2 = idx2[g];
    int gp = b * KP1 + p2;
    flag[q] = 0; flag[q + 256] = 0;
    __syncthreads();
    int n = kcnt[gp];
    if (q < n) flag[knbr[(size_t)gp * MAXD + q]] = 1;
    __syncthreads();
    int q2 = idx2[b * KP2 + q];
    float a1k = v1[b * KP1 + q2] * (flag[q2] ? (1.f + E1) : 1.f) / Z1[gp];
    float z = rv[b * KP2 + q] + a1k;
    red[q] = z;
    __syncthreads();
    for (int s = 128; s > 0; s >>= 1) {
        if (q < s) red[q] = fmaxf(red[q], red[q + s]);
        __syncthreads();
    }
    float mx = red[0];
    __syncthreads();
    float e = expf(z - mx);
    red[q] = e;
    __syncthreads();
    for (int s = 128; s > 0; s >>= 1) {
        if (q < s) red[q] += red[q + s];
        __syncthreads();
    }
    a2[(size_t)g * KP2 + q] = e / red[0];
}

// ---------------- merged: gemm3(gather h2) [0,256) | readout2 [256,512) | a2 [512,...) ----------------
__global__ __launch_bounds__(256, 4)
void k_gemm3_ro2_a2(const float* __restrict__ h2, const unsigned short* __restrict__ whi3,
                    const unsigned short* __restrict__ wlo3, float* __restrict__ t3,
                    float* __restrict__ rout, const int* __restrict__ idx2,
                    const float* __restrict__ rv, const float* __restrict__ v1,
                    const float* __restrict__ Z1, const int* __restrict__ knbr,
                    const int* __restrict__ kcnt, float* __restrict__ a2) {
    __shared__ __align__(16) char smem[33792];
    if (blockIdx.x < 256)
        gemm_body<NH, 8>(smem, h2, idx2, KP1, whi3, wlo3, t3, blockIdx.x);
    else if (blockIdx.x < 512)
        readout_body<KP2, false, KP1>(smem, h2, idx2, rout, blockIdx.x - 256);
    else a2_body(smem, idx2, rv, v1, Z1, knbr, kcnt, a2, blockIdx.x - 512);
}

// ---------------- fused stage-3: h3 = relu(0.5*(a2@t3 + t3) + b3) -> readout += ----------------
__global__ __launch_bounds__(256, 2)
void gcn3_fused_kernel(const float* __restrict__ a2, const float* __restrict__ t3,
                       const float* __restrict__ b3, float* __restrict__ rout) {
    constexpr int KC = 16;
    __shared__ float sa[KC][260];
    __shared__ float st[KC][32];
    int b = blockIdx.x >> 3;
    int cb = (blockIdx.x & 7) * 32;
    int tid = threadIdx.x;
    int ct = tid & 7, rt = tid >> 3;
    int c0 = cb + ct * 4, r0 = rt * 8;
    const float* ab = a2 + (size_t)b * KP2 * KP2;
    const float* tb = t3 + (size_t)b * KP2 * NH;
    float acc[8][4] = {};
    for (int q0 = 0; q0 < KP2; q0 += KC) {
        const float4* A4 = (const float4*)ab;
        for (int i = tid; i < 256 * (KC / 4); i += 256) {
            int r = i >> 2, j = i & 3;
            float4 v = A4[(size_t)r * 64 + q0 / 4 + j];
            sa[j * 4 + 0][r] = v.x; sa[j * 4 + 1][r] = v.y;
            sa[j * 4 + 2][r] = v.z; sa[j * 4 + 3][r] = v.w;
        }
        if (tid < KC * 8) {
            int q = tid >> 3, c4 = tid & 7;
            *(float4*)&st[q][c4 * 4] = *(const float4*)&tb[(size_t)(q0 + q) * NH + cb + c4 * 4];
        }
        __syncthreads();
        #pragma unroll
        for (int q = 0; q < KC; ++q) {
            float tv[4], av[8];
            *(float4*)&tv[0] = *(const float4*)&st[q][ct * 4];
            *(float4*)&av[0] = *(const float4*)&sa[q][r0];
            *(float4*)&av[4] = *(const float4*)&sa[q][r0 + 4];
            #pragma unroll
            for (int r = 0; r < 8; ++r)
                #pragma unroll
                for (int c = 0; c < 4; ++c)
                    acc[r][c] += av[r] * tv[c];
        }
        __syncthreads();
    }
    float bv[4];
    *(float4*)&bv[0] = *(const float4*)&b3[c0];
    float mx[4] = {-1e30f, -1e30f, -1e30f, -1e30f}, sm[4] = {};
    for (int r = 0; r < 8; ++r) {
        float4 t4 = *(const float4*)&tb[(size_t)(r0 + r) * NH + c0];
        float tvv[4] = {t4.x, t4.y, t4.z, t4.w};
        #pragma unroll
        for (int c = 0; c < 4; ++c) {
            float h = fmaxf(0.5f * (acc[r][c] + tvv[c]) + bv[c], 0.f);
            mx[c] = fmaxf(mx[c], h);
            sm[c] += h;
        }
    }
    __shared__ float rmx2[32][33], rsm2[32][33];
    #pragma unroll
    for (int c = 0; c < 4; ++c) { rmx2[ct * 4 + c][rt] = mx[c]; rsm2[ct * 4 + c][rt] = sm[c]; }
    __syncthreads();
    if (tid < 32) {
        float m = -1e30f, s = 0.f;
        for (int r = 0; r < 32; ++r) { m = fmaxf(m, rmx2[tid][r]); s += rsm2[tid][r]; }
        rout[b * 512 + cb + tid] += fmaxf(m, 0.f);
        rout[b * 512 + NH + cb + tid] += fmaxf(s * (1.f / KP2), 0.f);
    }
}

// ---------------- final linear ----------------
__global__ __launch_bounds__(256)
void final_kernel(const float* __restrict__ rout, const float* __restrict__ Wlin,
                  const float* __restrict__ blin, float* __restrict__ out) {
    int b = blockIdx.x;
    int tid = threadIdx.x;
    int c = tid & 15, fg = tid >> 4;
    float acc = 0.f;
    if (c < NCLS) {
        for (int k = 0; k < 32; ++k) {
            int f = fg * 32 + k;
            acc += rout[b * 512 + f] * Wlin[f * NCLS + c];
        }
    }
    __shared__ float red[16][16];
    red[fg][c] = acc;
    __syncthreads();
    if (tid < 16 && c < NCLS) {
        float a = blin[c];
        #pragma unroll
        for (int k = 0; k < 16; ++k) a += red[k][c];
        out[b * NCLS + c] = a;
    }
}

extern "C" void kernel_launch(void* const* d_in, const int* in_sizes, int n_in,
                              void* d_out, int out_size, void* d_ws, size_t ws_size,
                              hipStream_t stream) {
    const float* x    = (const float*)d_in[0];
    const float* adj  = (const float*)d_in[1];
    const float* W1   = (const float*)d_in[2];
    const float* b1   = (const float*)d_in[3];
    const float* W2   = (const float*)d_in[4];
    const float* b2   = (const float*)d_in[5];
    const float* W3   = (const float*)d_in[6];
    const float* b3   = (const float*)d_in[7];
    const float* att1 = (const float*)d_in[8];
    const float* att2 = (const float*)d_in[9];
    const float* Wlin = (const float*)d_in[10];
    const float* blin = (const float*)d_in[11];
    float* out = (float*)d_out;

    float* fws = (float*)d_ws;
    float* t1  = fws;                        // 8,388,608 floats
    float* h1  = t1 + 8388608;               // 8,388,608
    float* t2  = h1 + 8388608;               // 4,194,304
    float* dgi = t2 + 4194304;               // 32768
    float* dia = dgi + 32768;                // 32768
    float* sc  = dia + 32768;                // 32768
    float* rv  = sc + 32768;                 // 16384
    float* rout = rv + 16384;                // 16384
    float* v1  = rout + 16384;               // 16384
    float* V1  = v1 + 16384;                 // 64 (padded)
    float* Z1  = V1 + 64;                    // 16384
    float* wp  = Z1 + 16384;                 // 65536
    int* cnt  = (int*)(wp + 65536);          // 32768
    int* nbr  = cnt + 32768;                 // 2,097,152
    int* idx1 = nbr + 32768 * MAXD;          // 16384
    int* idx2 = idx1 + 16384;                // 8192
    int* pos1 = idx2 + 8192;                 // 32768
    unsigned short* whi1 = (unsigned short*)(pos1 + 32768);
    unsigned short* wlo1 = whi1 + 32768;
    unsigned short* whi2 = wlo1 + 32768;
    unsigned short* wlo2 = whi2 + 65536;
    unsigned short* whi3 = wlo2 + 65536;
    unsigned short* wlo3 = whi3 + 65536;
    int* qctr = (int*)(wlo3 + 65536);        // 32 ints: 4 kernels x 8 XCD queues
    // aliases (lifetime-disjoint reuse)
    float* h2   = h1;                        // h1 dead after gemm2's gather
    float* a2   = t1;                        // t1 dead after gcn1
    float* t3   = t1 + 2097152;
    int*   knbr = (int*)(t1 + 6291456);
    int*   kcnt = knbr + 16384 * MAXD;

    // ---- W pre-split + work-queue reset ----
    wsplit_kernel<<<640, 256, 0, stream>>>(W1, W2, W3, whi1, wlo1, whi2, wlo2,
                                           whi3, wlo3, qctr);

    // ---- stage 1: [gemm1 | csr] overlapped ----
    k_gemm1_csr<<<1024 + B * N1, 256, 0, stream>>>(x, whi1, wlo1, t1,
                                                   adj, cnt, nbr, dgi, dia);
    gcn1_kernel<<<2048, 256, 0, stream>>>(t1, cnt, nbr, dgi, b1, h1, qctr + 0);
    info1_kernel<<<2048, 256, 0, stream>>>(h1, cnt, nbr, dia, sc, qctr + 8);
    topk_kernel<N1, KP1, true><<<B, N1, 0, stream>>>(sc, idx1, pos1);
    rv_kernel<<<B * 128, 256, 0, stream>>>(h1, idx1, att1, rv, KP1, N1);
    k_readout1_vexp<<<288, 256, 0, stream>>>(h1, idx1, rout, rv, v1, V1);

    // ---- stage 2: [gemm2(gather) | knbr] overlapped ----
    k_gemm2_knbr<<<512 + B * 128, 256, 0, stream>>>(h1, whi2, wlo2, t2,
                                                    idx1, cnt, nbr, pos1, v1, V1,
                                                    knbr, kcnt, Z1);
    wsum_kernel<<<B * 8, 256, 0, stream>>>(t2, v1, wp);
    gcn2_kernel<<<1024, 256, 0, stream>>>(t2, wp, v1, Z1, knbr, kcnt, b2, h2, qctr + 16);
    wsum_kernel<<<B * 8, 256, 0, stream>>>(h2, v1, wp);
    info2_kernel<<<1024, 256, 0, stream>>>(h2, wp, v1, Z1, knbr, kcnt, sc, qctr + 24);
    topk_kernel<KP1, KP2, false><<<B, KP1, 0, stream>>>(sc, idx2, nullptr);
    rv_kernel<<<B * 64, 256, 0, stream>>>(h2, idx2, att2, rv, KP2, KP1);

    // ---- stage 3: [gemm3(gather) | readout2 | a2] overlapped ----
    k_gemm3_ro2_a2<<<512 + B * KP2, 256, 0, stream>>>(h2, whi3, wlo3, t3, rout,
                                                      idx2, rv, v1, Z1, knbr, kcnt, a2);
    gcn3_fused_kernel<<<B * 8, 256, 0, stream>>>(a2, t3, b3, rout);

    // ---- classifier ----
    final_kernel<<<B, 256, 0, stream>>>(rout, Wlin, blin, out);
}

// Round 15
// 262.771 us; speedup vs baseline: 1.2331x; 1.2331x over previous
//
#include <hip/hip_runtime.h>

#define B    32
#define N1   1024
#define FIN  128
#define NH   256
#define KP1  512
#define KP2  256
#define NCLS 10
#define MAXD 64
#define E1   1.7182818284590452f   // e^LAMB - 1, LAMB = 1.0

typedef float4 F4;
typedef __attribute__((ext_vector_type(8))) short bf16x8;
typedef __attribute__((ext_vector_type(4))) float f32x4;

__device__ __forceinline__ void fma4(F4& a, float s, F4 v) {
    a.x += s * v.x; a.y += s * v.y; a.z += s * v.z; a.w += s * v.w;
}
__device__ __forceinline__ void add4(F4& a, F4 v) {
    a.x += v.x; a.y += v.y; a.z += v.z; a.w += v.w;
}
__device__ __forceinline__ void max4(F4& a, F4 v) {
    a.x = fmaxf(a.x, v.x); a.y = fmaxf(a.y, v.y); a.z = fmaxf(a.z, v.z); a.w = fmaxf(a.w, v.w);
}
__device__ __forceinline__ unsigned short f2bf(float f) {
    unsigned int u = __float_as_uint(f);
    u += 0x7fffu + ((u >> 16) & 1u);
    return (unsigned short)(u >> 16);
}
__device__ __forceinline__ float bf2f(unsigned short h) {
    return __uint_as_float(((unsigned int)h) << 16);
}
__device__ __forceinline__ float wave_sum(float v) {
    v += __shfl_xor(v, 32); v += __shfl_xor(v, 16);
    v += __shfl_xor(v, 8);  v += __shfl_xor(v, 4);
    v += __shfl_xor(v, 2);  v += __shfl_xor(v, 1);
    return v;
}

// ---------------- W split into MFMA-fragment-order bf16 hi/lo ----------------
__global__ __launch_bounds__(256)
void wsplit_kernel(const float* __restrict__ W1, const float* __restrict__ W2,
                   const float* __restrict__ W3,
                   unsigned short* __restrict__ whi1, unsigned short* __restrict__ wlo1,
                   unsigned short* __restrict__ whi2, unsigned short* __restrict__ wlo2,
                   unsigned short* __restrict__ whi3, unsigned short* __restrict__ wlo3) {
    int T = blockIdx.x * 256 + threadIdx.x;   // 640 blocks -> 163840 elems
    const float* W; unsigned short *hi, *lo; int idx, kd;
    if (T < 32768)      { W = W1; hi = whi1; lo = wlo1; idx = T;         kd = 128; }
    else if (T < 98304) { W = W2; hi = whi2; lo = wlo2; idx = T - 32768; kd = 256; }
    else                { W = W3; hi = whi3; lo = wlo3; idx = T - 98304; kd = 256; }
    int e = idx & 7, lane = (idx >> 3) & 63;
    int nks = kd >> 5;
    int ks = (idx >> 9) & (nks - 1);
    int nt = idx >> ((nks == 4) ? 11 : 12);
    int k = ks * 32 + ((lane >> 4) << 3) + e;
    int j = nt * 16 + (lane & 15);
    float v = W[k * 256 + j];
    unsigned short h = f2bf(v);
    hi[idx] = h;
    lo[idx] = f2bf(v - bf2f(h));
}

// ---------------- MFMA GEMM body: out[32rows,256] = A @ W, bf16x3 split ----------------
// KLOG < 0: dense rows. KLOG >= 0: row gr comes from src[(gr>>KLOG)*nsrc + gidx[gr]]
template<int KD, int KLOG>
__device__ __forceinline__ void gemm_body(char* smem, const float* __restrict__ A,
                                          const int* __restrict__ gidx, int nsrc,
                                          const unsigned short* __restrict__ Whi,
                                          const unsigned short* __restrict__ Wlo,
                                          float* __restrict__ out, int blk) {
    constexpr int NKS = KD / 32;
    typedef unsigned short u16;
    auto ahi = (u16(*)[KD + 8])smem;
    auto alo = (u16(*)[KD + 8])(smem + sizeof(u16) * 32 * (KD + 8));
    int tid = threadIdx.x;
    int m0 = blk * 32;
    for (int i = tid; i < 32 * (KD / 4); i += 256) {
        int r = i / (KD / 4), c = i % (KD / 4);
        const float4* Arow;
        if (KLOG < 0) {
            Arow = (const float4*)(A + (size_t)(m0 + r) * KD);
        } else {
            int gr = m0 + r;
            int bb = gr >> (KLOG < 0 ? 0 : KLOG);
            Arow = (const float4*)(A + ((size_t)bb * nsrc + gidx[gr]) * KD);
        }
        float4 v = Arow[c];
        int k = c * 4;
        unsigned short h0 = f2bf(v.x), h1 = f2bf(v.y), h2 = f2bf(v.z), h3 = f2bf(v.w);
        *(uint2*)&ahi[r][k] = make_uint2((unsigned)h0 | ((unsigned)h1 << 16),
                                         (unsigned)h2 | ((unsigned)h3 << 16));
        unsigned short l0 = f2bf(v.x - bf2f(h0)), l1 = f2bf(v.y - bf2f(h1));
        unsigned short l2 = f2bf(v.z - bf2f(h2)), l3 = f2bf(v.w - bf2f(h3));
        *(uint2*)&alo[r][k] = make_uint2((unsigned)l0 | ((unsigned)l1 << 16),
                                         (unsigned)l2 | ((unsigned)l3 << 16));
    }
    __syncthreads();
    int lane = tid & 63, wv = tid >> 6;
    int ln15 = lane & 15, q = lane >> 4;
    f32x4 acc[2][4] = {};
    const bf16x8* WH = (const bf16x8*)Whi;
    const bf16x8* WL = (const bf16x8*)Wlo;
    for (int ks = 0; ks < NKS; ++ks) {
        int kb = ks * 32 + q * 8;
        bf16x8 a0h = *(const bf16x8*)&ahi[ln15][kb];
        bf16x8 a0l = *(const bf16x8*)&alo[ln15][kb];
        bf16x8 a1h = *(const bf16x8*)&ahi[ln15 + 16][kb];
        bf16x8 a1l = *(const bf16x8*)&alo[ln15 + 16][kb];
        #pragma unroll
        for (int t = 0; t < 4; ++t) {
            int nt = wv * 4 + t;
            size_t off = (size_t)(nt * NKS + ks) * 64 + lane;
            bf16x8 bh = WH[off];
            bf16x8 bl = WL[off];
            acc[0][t] = __builtin_amdgcn_mfma_f32_16x16x32_bf16(a0h, bh, acc[0][t], 0, 0, 0);
            acc[1][t] = __builtin_amdgcn_mfma_f32_16x16x32_bf16(a1h, bh, acc[1][t], 0, 0, 0);
            acc[0][t] = __builtin_amdgcn_mfma_f32_16x16x32_bf16(a0l, bh, acc[0][t], 0, 0, 0);
            acc[1][t] = __builtin_amdgcn_mfma_f32_16x16x32_bf16(a1l, bh, acc[1][t], 0, 0, 0);
            acc[0][t] = __builtin_amdgcn_mfma_f32_16x16x32_bf16(a0h, bl, acc[0][t], 0, 0, 0);
            acc[1][t] = __builtin_amdgcn_mfma_f32_16x16x32_bf16(a1h, bl, acc[1][t], 0, 0, 0);
        }
    }
    #pragma unroll
    for (int mi = 0; mi < 2; ++mi)
        #pragma unroll
        for (int t = 0; t < 4; ++t) {
            int col = wv * 64 + t * 16 + ln15;
            #pragma unroll
            for (int r = 0; r < 4; ++r)
                out[(size_t)(m0 + mi * 16 + q * 4 + r) * 256 + col] = acc[mi][t][r];
        }
}

// ---------------- CSR build body: wave-scan prefix, deterministic ----------------
__device__ __forceinline__ void csr_body(char* smem, const float* __restrict__ adj,
                                         int* __restrict__ cnt, int* __restrict__ nbr,
                                         float* __restrict__ dgi, float* __restrict__ dia,
                                         int row) {
    int* wtot = (int*)smem;
    const float* arow = adj + (size_t)row * N1;
    int t = threadIdx.x, lane = t & 63, wave = t >> 6;
    float4 v4 = ((const float4*)arow)[t];
    int loc[4];
    int c = 0;
    if (v4.x > 0.5f) loc[c++] = t * 4 + 0;
    if (v4.y > 0.5f) loc[c++] = t * 4 + 1;
    if (v4.z > 0.5f) loc[c++] = t * 4 + 2;
    if (v4.w > 0.5f) loc[c++] = t * 4 + 3;
    int x = c;
    #pragma unroll
    for (int s = 1; s < 64; s <<= 1) {
        int y = __shfl_up(x, s);
        if (lane >= s) x += y;
    }
    if (lane == 63) wtot[wave] = x;
    __syncthreads();
    int base = 0;
    #pragma unroll
    for (int w = 0; w < 4; ++w) base += (w < wave) ? wtot[w] : 0;
    int total = wtot[0] + wtot[1] + wtot[2] + wtot[3];
    int off = base + x - c;
    for (int u = 0; u < c; ++u) {
        int p = off + u;
        if (p < MAXD) nbr[(size_t)row * MAXD + p] = loc[u];
    }
    if (t == 0) {
        cnt[row] = min(total, MAXD);
        dgi[row] = rsqrtf((float)total + 1.0f);
        dia[row] = total > 0 ? 1.0f / (float)total : 0.0f;
    }
}

// ---------------- merged: gemm1 [0,1024) | csr [1024,1024+B*N1) ----------------
__global__ __launch_bounds__(256, 4)
void k_gemm1_csr(const float* __restrict__ x, const unsigned short* __restrict__ whi1,
                 const unsigned short* __restrict__ wlo1, float* __restrict__ t1,
                 const float* __restrict__ adj, int* __restrict__ cnt,
                 int* __restrict__ nbr, float* __restrict__ dgi, float* __restrict__ dia) {
    __shared__ __align__(16) char smem[17408];
    if (blockIdx.x < 1024) gemm_body<FIN, -1>(smem, x, nullptr, 0, whi1, wlo1, t1, blockIdx.x);
    else                   csr_body(smem, adj, cnt, nbr, dgi, dia, blockIdx.x - 1024);
}

// ---------------- stage-1 GCN aggregate: wave-per-row, seq-batch-per-XCD ----------------
__global__ __launch_bounds__(256)
void gcn1_kernel(const float* __restrict__ t1, const int* __restrict__ cnt,
                 const int* __restrict__ nbr, const float* __restrict__ dgi,
                 const float* __restrict__ b1, float* __restrict__ h1) {
    int blk = blockIdx.x;
    int xcd = blk & 7, rest = blk >> 3;
    int b = xcd * 4 + (rest >> 8);
    int g = rest & 255;
    int lane = threadIdx.x & 63, wave = threadIdx.x >> 6;
    int i = g * 4 + wave;
    int row = (b << 10) + i;
    const F4* tb = (const F4*)(t1 + (((size_t)b << 10)) * NH);
    int n = cnt[row];
    int jv = 0; float dv = 0.f;
    if (lane < n) {
        jv = nbr[(size_t)row * MAXD + lane];
        dv = dgi[(b << 10) + jv];
    }
    F4 a[8];
    #pragma unroll
    for (int k = 0; k < 8; ++k) a[k] = make_float4(0, 0, 0, 0);
    int e = 0;
    for (; e + 8 <= n; e += 8) {
        int jj[8]; float dd[8];
        #pragma unroll
        for (int k = 0; k < 8; ++k) { jj[k] = __shfl(jv, e + k); dd[k] = __shfl(dv, e + k); }
        F4 v[8];
        #pragma unroll
        for (int k = 0; k < 8; ++k) v[k] = tb[(size_t)jj[k] * 64 + lane];
        #pragma unroll
        for (int k = 0; k < 8; ++k) fma4(a[k], dd[k], v[k]);
    }
    for (; e + 4 <= n; e += 4) {
        int jj[4]; float dd[4];
        #pragma unroll
        for (int k = 0; k < 4; ++k) { jj[k] = __shfl(jv, e + k); dd[k] = __shfl(dv, e + k); }
        #pragma unroll
        for (int k = 0; k < 4; ++k) fma4(a[k], dd[k], tb[(size_t)jj[k] * 64 + lane]);
    }
    for (; e < n; ++e) {
        int j = __shfl(jv, e); float d = __shfl(dv, e);
        fma4(a[0], d, tb[(size_t)j * 64 + lane]);
    }
    add4(a[0], a[1]); add4(a[2], a[3]); add4(a[4], a[5]); add4(a[6], a[7]);
    add4(a[0], a[2]); add4(a[4], a[6]); add4(a[0], a[4]);
    float di = dgi[row];
    F4 self = tb[(size_t)i * 64 + lane];
    F4 bb = ((const F4*)b1)[lane];
    F4 r;
    r.x = fmaxf(di * (a[0].x + di * self.x) + bb.x, 0.f);
    r.y = fmaxf(di * (a[0].y + di * self.y) + bb.y, 0.f);
    r.z = fmaxf(di * (a[0].z + di * self.z) + bb.z, 0.f);
    r.w = fmaxf(di * (a[0].w + di * self.w) + bb.w, 0.f);
    ((F4*)(h1 + (size_t)row * NH))[lane] = r;
}

// ---------------- stage-1 info score: wave-per-row, seq-batch-per-XCD ----------------
__global__ __launch_bounds__(256)
void info1_kernel(const float* __restrict__ h1, const int* __restrict__ cnt,
                  const int* __restrict__ nbr, const float* __restrict__ dia,
                  float* __restrict__ sc) {
    int blk = blockIdx.x;
    int xcd = blk & 7, rest = blk >> 3;
    int b = xcd * 4 + (rest >> 8);
    int g = rest & 255;
    int lane = threadIdx.x & 63, wave = threadIdx.x >> 6;
    int i = g * 4 + wave;
    int row = (b << 10) + i;
    const F4* hb = (const F4*)(h1 + (((size_t)b << 10)) * NH);
    int n = cnt[row];
    int jv = 0;
    if (lane < n) jv = nbr[(size_t)row * MAXD + lane];
    F4 a[8];
    #pragma unroll
    for (int k = 0; k < 8; ++k) a[k] = make_float4(0, 0, 0, 0);
    int e = 0;
    for (; e + 8 <= n; e += 8) {
        int jj[8];
        #pragma unroll
        for (int k = 0; k < 8; ++k) jj[k] = __shfl(jv, e + k);
        F4 v[8];
        #pragma unroll
        for (int k = 0; k < 8; ++k) v[k] = hb[(size_t)jj[k] * 64 + lane];
        #pragma unroll
        for (int k = 0; k < 8; ++k) add4(a[k], v[k]);
    }
    for (; e + 4 <= n; e += 4) {
        int jj[4];
        #pragma unroll
        for (int k = 0; k < 4; ++k) jj[k] = __shfl(jv, e + k);
        #pragma unroll
        for (int k = 0; k < 4; ++k) add4(a[k], hb[(size_t)jj[k] * 64 + lane]);
    }
    for (; e < n; ++e) {
        int j = __shfl(jv, e);
        add4(a[0], hb[(size_t)j * 64 + lane]);
    }
    add4(a[0], a[1]); add4(a[2], a[3]); add4(a[4], a[5]); add4(a[6], a[7]);
    add4(a[0], a[2]); add4(a[4], a[6]); add4(a[0], a[4]);
    float dd = dia[row];
    F4 self = hb[(size_t)i * 64 + lane];
    float val = fabsf(self.x - dd * a[0].x) + fabsf(self.y - dd * a[0].y)
              + fabsf(self.z - dd * a[0].z) + fabsf(self.w - dd * a[0].w);
    val = wave_sum(val);
    if (lane == 0) sc[row] = val;
}

// ---------------- top-k: hybrid shfl/LDS bitonic, 1 elem/thread ----------------
template<int NS, int KS, bool POS>
__global__ __launch_bounds__(NS)
void topk_kernel(const float* __restrict__ sc, int* __restrict__ idxo,
                 int* __restrict__ pos) {
    int b = blockIdx.x, tid = threadIdx.x;
    __shared__ float ss[NS];
    __shared__ int si[NS];
    float s = sc[b * NS + tid];
    int id = tid;
    for (int ksz = 2; ksz <= NS; ksz <<= 1) {
        for (int j = ksz >> 1; j > 0; j >>= 1) {
            float so; int io;
            if (j >= 64) {
                ss[tid] = s; si[tid] = id;
                __syncthreads();
                so = ss[tid ^ j]; io = si[tid ^ j];
                __syncthreads();
            } else {
                so = __shfl_xor(s, j); io = __shfl_xor(id, j);
            }
            bool mineFirst = (s > so) || (s == so && id < io);
            bool amLower = (tid & j) == 0;
            bool dirDesc = (tid & ksz) == 0;
            bool keep = dirDesc ? (amLower ? mineFirst : !mineFirst)
                                : (amLower ? !mineFirst : mineFirst);
            if (!keep) { s = so; id = io; }
        }
    }
    if (tid < KS) idxo[b * KS + tid] = id;
    if (POS) pos[b * NS + id] = (tid < KS) ? tid : -1;
}

// ---------------- attention r-dot over pooled rows (no copy) ----------------
__global__ __launch_bounds__(256)
void rv_kernel(const float* __restrict__ h, const int* __restrict__ idx,
               const float* __restrict__ att, float* __restrict__ rv, int K, int Nsrc) {
    int blk = blockIdx.x;
    int b = blk & 31, g = blk >> 5;
    int lane = threadIdx.x & 63, wave = threadIdx.x >> 6;
    int p = g * 4 + wave;
    int gg = b * K + p;
    int src = idx[gg];
    F4 v = ((const F4*)(h + ((size_t)b * Nsrc + src) * NH))[lane];
    F4 ar = ((const F4*)att)[64 + lane];
    float r2 = wave_sum(v.x * ar.x + v.y * ar.y + v.z * ar.z + v.w * ar.w);
    if (lane == 0) rv[gg] = r2;
}

// ---------------- readout body (gathers rows through idx): relu(max)/relu(mean) ----------------
template<int NROWS, bool INIT, int NSRC>
__device__ __forceinline__ void readout_body(char* smem, const float* __restrict__ h,
                                             const int* __restrict__ idx,
                                             float* __restrict__ rout, int blk) {
    auto rmx = (F4(*)[9])smem;
    auto rsm = (F4(*)[9])(smem + 32 * 9 * sizeof(F4));
    int b = blk & 31, ch = blk >> 5;
    int c = threadIdx.x & 7, rg = threadIdx.x >> 3;
    int f4 = ch * 8 + c;
    F4 mx = make_float4(-1e30f, -1e30f, -1e30f, -1e30f);
    F4 sm = make_float4(0, 0, 0, 0);
    for (int r = rg; r < NROWS; r += 32) {
        int src = idx[b * NROWS + r];
        F4 v = ((const F4*)(h + ((size_t)b * NSRC + src) * NH))[f4];
        max4(mx, v); add4(sm, v);
    }
    rmx[rg][c] = mx; rsm[rg][c] = sm;
    __syncthreads();
    for (int s = 16; s > 0; s >>= 1) {
        if (rg < s) {
            F4 m2 = rmx[rg + s][c], s2 = rsm[rg + s][c];
            max4(rmx[rg][c], m2); add4(rsm[rg][c], s2);
        }
        __syncthreads();
    }
    if (rg == 0) {
        F4 m = rmx[0][c], s4 = rsm[0][c];
        F4 rm, ra;
        rm.x = fmaxf(m.x, 0.f); rm.y = fmaxf(m.y, 0.f); rm.z = fmaxf(m.z, 0.f); rm.w = fmaxf(m.w, 0.f);
        const float inv = 1.0f / NROWS;
        ra.x = fmaxf(s4.x * inv, 0.f); ra.y = fmaxf(s4.y * inv, 0.f);
        ra.z = fmaxf(s4.z * inv, 0.f); ra.w = fmaxf(s4.w * inv, 0.f);
        F4* ro = (F4*)(rout + b * 512);
        if (INIT) {
            ro[f4] = rm; ro[64 + f4] = ra;
        } else {
            F4 o1 = ro[f4], o2 = ro[64 + f4];
            add4(o1, rm); add4(o2, ra);
            ro[f4] = o1; ro[64 + f4] = o2;
        }
    }
}

// ---------------- vexp body (256 threads, 2 elems each) ----------------
__device__ __forceinline__ void vexp_body(char* smem, const float* __restrict__ rv,
                                          float* __restrict__ v1, float* __restrict__ V1,
                                          int b) {
    float* red = (float*)smem;
    int t = threadIdx.x;
    float r0 = rv[b * KP1 + t], r1 = rv[b * KP1 + 256 + t];
    red[t] = fmaxf(r0, r1);
    __syncthreads();
    for (int s = 128; s > 0; s >>= 1) {
        if (t < s) red[t] = fmaxf(red[t], red[t + s]);
        __syncthreads();
    }
    float mx = red[0];
    __syncthreads();
    float e0 = expf(r0 - mx), e1 = expf(r1 - mx);
    v1[b * KP1 + t] = e0;
    v1[b * KP1 + 256 + t] = e1;
    red[t] = e0 + e1;
    __syncthreads();
    for (int s = 128; s > 0; s >>= 1) {
        if (t < s) red[t] += red[t + s];
        __syncthreads();
    }
    if (t == 0) V1[b] = red[0];
}

// ---------------- merged: readout1 [0,256) | vexp [256,288) ----------------
__global__ __launch_bounds__(256)
void k_readout1_vexp(const float* __restrict__ h1, const int* __restrict__ idx1,
                     float* __restrict__ rout, const float* __restrict__ rv,
                     float* __restrict__ v1, float* __restrict__ V1) {
    __shared__ __align__(16) char smem[9216];
    if (blockIdx.x < 256) readout_body<KP1, true, N1>(smem, h1, idx1, rout, blockIdx.x);
    else                  vexp_body(smem, rv, v1, V1, blockIdx.x - 256);
}

// ---------------- knbr body (4 waves/block) ----------------
__device__ __forceinline__ void knbr_body(const int* __restrict__ idx1, const int* __restrict__ cnt,
                                          const int* __restrict__ nbr, const int* __restrict__ pos1,
                                          const float* __restrict__ v1, const float* __restrict__ V1,
                                          int* __restrict__ knbr, int* __restrict__ kcnt,
                                          float* __restrict__ Z1, int j) {
    int b = j & 31, pg = j >> 5;
    int lane = threadIdx.x & 63, wave = threadIdx.x >> 6;
    int p = pg * 4 + wave;
    int g = b * KP1 + p;
    int ip = idx1[g];
    int n = cnt[b * N1 + ip];
    int q = -1;
    if (lane < n) {
        int jj = nbr[(size_t)(b * N1 + ip) * MAXD + lane];
        q = pos1[b * N1 + jj];
    }
    bool kept = q >= 0;
    unsigned long long mask = __ballot(kept);
    int off = __popcll(mask & ((1ull << lane) - 1ull));
    if (kept) knbr[(size_t)g * MAXD + off] = q;
    float s = kept ? v1[b * KP1 + q] : 0.f;
    s = wave_sum(s);
    if (lane == 0) { kcnt[g] = __popcll(mask); Z1[g] = V1[b] + E1 * s; }
}

// ---------------- merged: gemm2(gather h1) [0,512) | knbr [512,512+B*128) ----------------
__global__ __launch_bounds__(256, 4)
void k_gemm2_knbr(const float* __restrict__ h1, const unsigned short* __restrict__ whi2,
                  const unsigned short* __restrict__ wlo2, float* __restrict__ t2,
                  const int* __restrict__ idx1, const int* __restrict__ cnt,
                  const int* __restrict__ nbr, const int* __restrict__ pos1,
                  const float* __restrict__ v1, const float* __restrict__ V1,
                  int* __restrict__ knbr, int* __restrict__ kcnt, float* __restrict__ Z1) {
    __shared__ __align__(16) char smem[33792];
    if (blockIdx.x < 512)
        gemm_body<NH, 9>(smem, h1, idx1, N1, whi2, wlo2, t2, blockIdx.x);
    else knbr_body(idx1, cnt, nbr, pos1, v1, V1, knbr, kcnt, Z1, blockIdx.x - 512);
}

// ---------------- per-batch weighted column sum (partials over 8 chunks) ----------------
__global__ __launch_bounds__(256)
void wsum_kernel(const float* __restrict__ X, const float* __restrict__ v1,
                 float* __restrict__ wp) {
    int blk = blockIdx.x;
    int b = blk >> 3, c = blk & 7;
    int f = threadIdx.x;
    float a0 = 0.f, a1 = 0.f, a2 = 0.f, a3 = 0.f;
    for (int q = c * 64; q < c * 64 + 64; q += 4) {
        a0 += v1[b * KP1 + q + 0] * X[(size_t)(b * KP1 + q + 0) * NH + f];
        a1 += v1[b * KP1 + q + 1] * X[(size_t)(b * KP1 + q + 1) * NH + f];
        a2 += v1[b * KP1 + q + 2] * X[(size_t)(b * KP1 + q + 2) * NH + f];
        a3 += v1[b * KP1 + q + 3] * X[(size_t)(b * KP1 + q + 3) * NH + f];
    }
    wp[(size_t)blk * NH + f] = (a0 + a1) + (a2 + a3);
}

// ---------------- stage-2 GCN via factorized a1: wave-per-row ----------------
__global__ __launch_bounds__(256)
void gcn2_kernel(const float* __restrict__ t2, const float* __restrict__ wp,
                 const float* __restrict__ v1, const float* __restrict__ Z1,
                 const int* __restrict__ knbr, const int* __restrict__ kcnt,
                 const float* __restrict__ b2, float* __restrict__ h2) {
    int blk = blockIdx.x;
    int xcd = blk & 7, rest = blk >> 3;
    int b = xcd * 4 + (rest >> 7);
    int g = rest & 127;
    int lane = threadIdx.x & 63, wave = threadIdx.x >> 6;
    int p = g * 4 + wave;
    int gg = (b << 9) + p;
    const F4* tb = (const F4*)(t2 + (((size_t)b << 9)) * NH);
    int n = kcnt[gg];
    int jv = 0; float wv = 0.f;
    if (lane < n) {
        jv = knbr[(size_t)gg * MAXD + lane];
        wv = v1[(b << 9) + jv];
    }
    F4 a0 = make_float4(0,0,0,0), a1 = a0, a2 = a0, a3 = a0;
    int e = 0;
    for (; e + 4 <= n; e += 4) {
        int j0 = __shfl(jv, e), j1 = __shfl(jv, e+1), j2 = __shfl(jv, e+2), j3 = __shfl(jv, e+3);
        float d0 = __shfl(wv, e), d1 = __shfl(wv, e+1), d2 = __shfl(wv, e+2), d3 = __shfl(wv, e+3);
        fma4(a0, d0, tb[(size_t)j0 * 64 + lane]); fma4(a1, d1, tb[(size_t)j1 * 64 + lane]);
        fma4(a2, d2, tb[(size_t)j2 * 64 + lane]); fma4(a3, d3, tb[(size_t)j3 * 64 + lane]);
    }
    for (; e < n; ++e) {
        int j = __shfl(jv, e); float d = __shfl(wv, e);
        fma4(a0, d, tb[(size_t)j * 64 + lane]);
    }
    add4(a0, a1); add4(a2, a3); add4(a0, a2);
    F4 w = make_float4(0,0,0,0);
    #pragma unroll
    for (int c = 0; c < 8; ++c) add4(w, ((const F4*)wp)[(size_t)(b * 8 + c) * 64 + lane]);
    float zi = 1.0f / Z1[gg];
    F4 tv = tb[(size_t)p * 64 + lane];
    F4 bb = ((const F4*)b2)[lane];
    F4 r;
    r.x = fmaxf(0.5f * ((w.x + E1 * a0.x) * zi + tv.x) + bb.x, 0.f);
    r.y = fmaxf(0.5f * ((w.y + E1 * a0.y) * zi + tv.y) + bb.y, 0.f);
    r.z = fmaxf(0.5f * ((w.z + E1 * a0.z) * zi + tv.z) + bb.z, 0.f);
    r.w = fmaxf(0.5f * ((w.w + E1 * a0.w) * zi + tv.w) + bb.w, 0.f);
    ((F4*)(h2 + (size_t)gg * NH))[lane] = r;
}

// ---------------- stage-2 info score via factorized a1: wave-per-row ----------------
__global__ __launch_bounds__(256)
void info2_kernel(const float* __restrict__ h2, const float* __restrict__ wp,
                  const float* __restrict__ v1, const float* __restrict__ Z1,
                  const int* __restrict__ knbr, const int* __restrict__ kcnt,
                  float* __restrict__ sc) {
    int blk = blockIdx.x;
    int xcd = blk & 7, rest = blk >> 3;
    int b = xcd * 4 + (rest >> 7);
    int g = rest & 127;
    int lane = threadIdx.x & 63, wave = threadIdx.x >> 6;
    int p = g * 4 + wave;
    int gg = (b << 9) + p;
    const F4* hb = (const F4*)(h2 + (((size_t)b << 9)) * NH);
    int n = kcnt[gg];
    int jv = 0; float wv = 0.f;
    if (lane < n) {
        jv = knbr[(size_t)gg * MAXD + lane];
        wv = v1[(b << 9) + jv];
    }
    F4 a0 = make_float4(0,0,0,0), a1 = a0, a2 = a0, a3 = a0;
    int e = 0;
    for (; e + 4 <= n; e += 4) {
        int j0 = __shfl(jv, e), j1 = __shfl(jv, e+1), j2 = __shfl(jv, e+2), j3 = __shfl(jv, e+3);
        float d0 = __shfl(wv, e), d1 = __shfl(wv, e+1), d2 = __shfl(wv, e+2), d3 = __shfl(wv, e+3);
        fma4(a0, d0, hb[(size_t)j0 * 64 + lane]); fma4(a1, d1, hb[(size_t)j1 * 64 + lane]);
        fma4(a2, d2, hb[(size_t)j2 * 64 + lane]); fma4(a3, d3, hb[(size_t)j3 * 64 + lane]);
    }
    for (; e < n; ++e) {
        int j = __shfl(jv, e); float d = __shfl(wv, e);
        fma4(a0, d, hb[(size_t)j * 64 + lane]);
    }
    add4(a0, a1); add4(a2, a3); add4(a0, a2);
    F4 w = make_float4(0,0,0,0);
    #pragma unroll
    for (int c = 0; c < 8; ++c) add4(w, ((const F4*)wp)[(size_t)(b * 8 + c) * 64 + lane]);
    float zi = 1.0f / Z1[gg];
    F4 self = hb[(size_t)p * 64 + lane];
    float val = fabsf(self.x - (w.x + E1 * a0.x) * zi) + fabsf(self.y - (w.y + E1 * a0.y) * zi)
              + fabsf(self.z - (w.z + E1 * a0.z) * zi) + fabsf(self.w - (w.w + E1 * a0.w) * zi);
    val = wave_sum(val);
    if (lane == 0) sc[gg] = val;
}

// ---------------- a2 body: softmax(r2_q + a1k[p,q]) ----------------
__device__ __forceinline__ void a2_body(char* smem, const int* __restrict__ idx2,
                                        const float* __restrict__ rv, const float* __restrict__ v1,
                                        const float* __restrict__ Z1, const int* __restrict__ knbr,
                                        const int* __restrict__ kcnt, float* __restrict__ a2,
                                        int j) {
    unsigned char* flag = (unsigned char*)smem;
    float* red = (float*)(smem + 512);
    int b = j & 31, p = j >> 5;
    int g = b * KP2 + p;
    int q = threadIdx.x;
    int p2 = idx2[g];
    int gp = b * KP1 + p2;
    flag[q] = 0; flag[q + 256] = 0;
    __syncthreads();
    int n = kcnt[gp];
    if (q < n) flag[knbr[(size_t)gp * MAXD + q]] = 1;
    __syncthreads();
    int q2 = idx2[b * KP2 + q];
    float a1k = v1[b * KP1 + q2] * (flag[q2] ? (1.f + E1) : 1.f) / Z1[gp];
    float z = rv[b * KP2 + q] + a1k;
    red[q] = z;
    __syncthreads();
    for (int s = 128; s > 0; s >>= 1) {
        if (q < s) red[q] = fmaxf(red[q], red[q + s]);
        __syncthreads();
    }
    float mx = red[0];
    __syncthreads();
    float e = expf(z - mx);
    red[q] = e;
    __syncthreads();
    for (int s = 128; s > 0; s >>= 1) {
        if (q < s) red[q] += red[q + s];
        __syncthreads();
    }
    a2[(size_t)g * KP2 + q] = e / red[0];
}

// ---------------- merged: gemm3(gather h2) [0,256) | readout2 [256,512) | a2 [512,...) ----------------
__global__ __launch_bounds__(256, 4)
void k_gemm3_ro2_a2(const float* __restrict__ h2, const unsigned short* __restrict__ whi3,
                    const unsigned short* __restrict__ wlo3, float* __restrict__ t3,
                    float* __restrict__ rout, const int* __restrict__ idx2,
                    const float* __restrict__ rv, const float* __restrict__ v1,
                    const float* __restrict__ Z1, const int* __restrict__ knbr,
                    const int* __restrict__ kcnt, float* __restrict__ a2) {
    __shared__ __align__(16) char smem[33792];
    if (blockIdx.x < 256)
        gemm_body<NH, 8>(smem, h2, idx2, KP1, whi3, wlo3, t3, blockIdx.x);
    else if (blockIdx.x < 512)
        readout_body<KP2, false, KP1>(smem, h2, idx2, rout, blockIdx.x - 256);
    else a2_body(smem, idx2, rv, v1, Z1, knbr, kcnt, a2, blockIdx.x - 512);
}

// ---------------- fused stage-3: h3 = relu(0.5*(a2@t3 + t3) + b3) -> readout += ----------------
__global__ __launch_bounds__(256, 2)
void gcn3_fused_kernel(const float* __restrict__ a2, const float* __restrict__ t3,
                       const float* __restrict__ b3, float* __restrict__ rout) {
    constexpr int KC = 16;
    __shared__ float sa[KC][260];
    __shared__ float st[KC][32];
    int b = blockIdx.x >> 3;
    int cb = (blockIdx.x & 7) * 32;
    int tid = threadIdx.x;
    int ct = tid & 7, rt = tid >> 3;
    int c0 = cb + ct * 4, r0 = rt * 8;
    const float* ab = a2 + (size_t)b * KP2 * KP2;
    const float* tb = t3 + (size_t)b * KP2 * NH;
    float acc[8][4] = {};
    for (int q0 = 0; q0 < KP2; q0 += KC) {
        const float4* A4 = (const float4*)ab;
        for (int i = tid; i < 256 * (KC / 4); i += 256) {
            int r = i >> 2, j = i & 3;
            float4 v = A4[(size_t)r * 64 + q0 / 4 + j];
            sa[j * 4 + 0][r] = v.x; sa[j * 4 + 1][r] = v.y;
            sa[j * 4 + 2][r] = v.z; sa[j * 4 + 3][r] = v.w;
        }
        if (tid < KC * 8) {
            int q = tid >> 3, c4 = tid & 7;
            *(float4*)&st[q][c4 * 4] = *(const float4*)&tb[(size_t)(q0 + q) * NH + cb + c4 * 4];
        }
        __syncthreads();
        #pragma unroll
        for (int q = 0; q < KC; ++q) {
            float tv[4], av[8];
            *(float4*)&tv[0] = *(const float4*)&st[q][ct * 4];
            *(float4*)&av[0] = *(const float4*)&sa[q][r0];
            *(float4*)&av[4] = *(const float4*)&sa[q][r0 + 4];
            #pragma unroll
            for (int r = 0; r < 8; ++r)
                #pragma unroll
                for (int c = 0; c < 4; ++c)
                    acc[r][c] += av[r] * tv[c];
        }
        __syncthreads();
    }
    float bv[4];
    *(float4*)&bv[0] = *(const float4*)&b3[c0];
    float mx[4] = {-1e30f, -1e30f, -1e30f, -1e30f}, sm[4] = {};
    for (int r = 0; r < 8; ++r) {
        float4 t4 = *(const float4*)&tb[(size_t)(r0 + r) * NH + c0];
        float tvv[4] = {t4.x, t4.y, t4.z, t4.w};
        #pragma unroll
        for (int c = 0; c < 4; ++c) {
            float h = fmaxf(0.5f * (acc[r][c] + tvv[c]) + bv[c], 0.f);
            mx[c] = fmaxf(mx[c], h);
            sm[c] += h;
        }
    }
    __shared__ float rmx2[32][33], rsm2[32][33];
    #pragma unroll
    for (int c = 0; c < 4; ++c) { rmx2[ct * 4 + c][rt] = mx[c]; rsm2[ct * 4 + c][rt] = sm[c]; }
    __syncthreads();
    if (tid < 32) {
        float m = -1e30f, s = 0.f;
        for (int r = 0; r < 32; ++r) { m = fmaxf(m, rmx2[tid][r]); s += rsm2[tid][r]; }
        rout[b * 512 + cb + tid] += fmaxf(m, 0.f);
        rout[b * 512 + NH + cb + tid] += fmaxf(s * (1.f / KP2), 0.f);
    }
}

// ---------------- final linear ----------------
__global__ __launch_bounds__(256)
void final_kernel(const float* __restrict__ rout, const float* __restrict__ Wlin,
                  const float* __restrict__ blin, float* __restrict__ out) {
    int b = blockIdx.x;
    int tid = threadIdx.x;
    int c = tid & 15, fg = tid >> 4;
    float acc = 0.f;
    if (c < NCLS) {
        for (int k = 0; k < 32; ++k) {
            int f = fg * 32 + k;
            acc += rout[b * 512 + f] * Wlin[f * NCLS + c];
        }
    }
    __shared__ float red[16][16];
    red[fg][c] = acc;
    __syncthreads();
    if (tid < 16 && c < NCLS) {
        float a = blin[c];
        #pragma unroll
        for (int k = 0; k < 16; ++k) a += red[k][c];
        out[b * NCLS + c] = a;
    }
}

extern "C" void kernel_launch(void* const* d_in, const int* in_sizes, int n_in,
                              void* d_out, int out_size, void* d_ws, size_t ws_size,
                              hipStream_t stream) {
    const float* x    = (const float*)d_in[0];
    const float* adj  = (const float*)d_in[1];
    const float* W1   = (const float*)d_in[2];
    const float* b1   = (const float*)d_in[3];
    const float* W2   = (const float*)d_in[4];
    const float* b2   = (const float*)d_in[5];
    const float* W3   = (const float*)d_in[6];
    const float* b3   = (const float*)d_in[7];
    const float* att1 = (const float*)d_in[8];
    const float* att2 = (const float*)d_in[9];
    const float* Wlin = (const float*)d_in[10];
    const float* blin = (const float*)d_in[11];
    float* out = (float*)d_out;

    float* fws = (float*)d_ws;
    float* t1  = fws;                        // 8,388,608 floats
    float* h1  = t1 + 8388608;               // 8,388,608
    float* t2  = h1 + 8388608;               // 4,194,304
    float* dgi = t2 + 4194304;               // 32768
    float* dia = dgi + 32768;                // 32768
    float* sc  = dia + 32768;                // 32768
    float* rv  = sc + 32768;                 // 16384
    float* rout = rv + 16384;                // 16384
    float* v1  = rout + 16384;               // 16384
    float* V1  = v1 + 16384;                 // 64 (padded)
    float* Z1  = V1 + 64;                    // 16384
    float* wp  = Z1 + 16384;                 // 65536
    int* cnt  = (int*)(wp + 65536);          // 32768
    int* nbr  = cnt + 32768;                 // 2,097,152
    int* idx1 = nbr + 32768 * MAXD;          // 16384
    int* idx2 = idx1 + 16384;                // 8192
    int* pos1 = idx2 + 8192;                 // 32768
    unsigned short* whi1 = (unsigned short*)(pos1 + 32768);
    unsigned short* wlo1 = whi1 + 32768;
    unsigned short* whi2 = wlo1 + 32768;
    unsigned short* wlo2 = whi2 + 65536;
    unsigned short* whi3 = wlo2 + 65536;
    unsigned short* wlo3 = whi3 + 65536;
    // aliases (lifetime-disjoint reuse)
    float* h2   = h1;                        // h1 dead after gemm2's gather
    float* a2   = t1;                        // t1 dead after gcn1
    float* t3   = t1 + 2097152;
    int*   knbr = (int*)(t1 + 6291456);
    int*   kcnt = knbr + 16384 * MAXD;

    // ---- W pre-split ----
    wsplit_kernel<<<640, 256, 0, stream>>>(W1, W2, W3, whi1, wlo1, whi2, wlo2, whi3, wlo3);

    // ---- stage 1: [gemm1 | csr] overlapped ----
    k_gemm1_csr<<<1024 + B * N1, 256, 0, stream>>>(x, whi1, wlo1, t1,
                                                   adj, cnt, nbr, dgi, dia);
    gcn1_kernel<<<B * 256, 256, 0, stream>>>(t1, cnt, nbr, dgi, b1, h1);
    info1_kernel<<<B * 256, 256, 0, stream>>>(h1, cnt, nbr, dia, sc);
    topk_kernel<N1, KP1, true><<<B, N1, 0, stream>>>(sc, idx1, pos1);
    rv_kernel<<<B * 128, 256, 0, stream>>>(h1, idx1, att1, rv, KP1, N1);
    k_readout1_vexp<<<288, 256, 0, stream>>>(h1, idx1, rout, rv, v1, V1);

    // ---- stage 2: [gemm2(gather) | knbr] overlapped ----
    k_gemm2_knbr<<<512 + B * 128, 256, 0, stream>>>(h1, whi2, wlo2, t2,
                                                    idx1, cnt, nbr, pos1, v1, V1,
                                                    knbr, kcnt, Z1);
    wsum_kernel<<<B * 8, 256, 0, stream>>>(t2, v1, wp);
    gcn2_kernel<<<B * 128, 256, 0, stream>>>(t2, wp, v1, Z1, knbr, kcnt, b2, h2);
    wsum_kernel<<<B * 8, 256, 0, stream>>>(h2, v1, wp);
    info2_kernel<<<B * 128, 256, 0, stream>>>(h2, wp, v1, Z1, knbr, kcnt, sc);
    topk_kernel<KP1, KP2, false><<<B, KP1, 0, stream>>>(sc, idx2, nullptr);
    rv_kernel<<<B * 64, 256, 0, stream>>>(h2, idx2, att2, rv, KP2, KP1);

    // ---- stage 3: [gemm3(gather) | readout2 | a2] overlapped ----
    k_gemm3_ro2_a2<<<512 + B * KP2, 256, 0, stream>>>(h2, whi3, wlo3, t3, rout,
                                                      idx2, rv, v1, Z1, knbr, kcnt, a2);
    gcn3_fused_kernel<<<B * 8, 256, 0, stream>>>(a2, t3, b3, rout);

    // ---- classifier ----
    final_kernel<<<B, 256, 0, stream>>>(rout, Wlin, blin, out);
}